// Round 1
// baseline (2945.883 us; speedup 1.0000x reference)
//
#include <hip/hip_runtime.h>

#define TPB 256

// ---------------- degree / normalization ----------------

__global__ void k_deg_init(float* __restrict__ deg, int n) {
    int i = blockIdx.x * TPB + threadIdx.x;
    if (i < n) deg[i] = 1.0f;  // self-loop contributes 1
}

__global__ void k_deg_count(const int* __restrict__ dst, float* __restrict__ deg, int E) {
    int e = blockIdx.x * TPB + threadIdx.x;
    if (e < E) atomicAdd(&deg[dst[e]], 1.0f);
}

__global__ void k_dinv(float* __restrict__ deg, int n) {
    int i = blockIdx.x * TPB + threadIdx.x;
    if (i < n) deg[i] = rsqrtf(deg[i]);  // deg >= 1 always (self-loop)
}

// ---------------- W transpose (one-time, 64 KB) ----------------
// Wt[k][j] = W[j][k] so GEMM staging is coalesced + conflict-free.

__global__ void k_transpose(const float* __restrict__ W, float* __restrict__ Wt) {
    int idx = blockIdx.x * TPB + threadIdx.x;
    if (idx < 128 * 128) {
        int j = idx >> 7, k = idx & 127;
        Wt[k * 128 + j] = W[idx];
    }
}

// ---------------- GEMM: g[i][j] = dinv[i] * sum_k x[i][k] * W[j][k] ----------------
// Block tile: 32 rows x 128 cols, K split into 2 passes of 64.
// 256 threads: tx=tid&31 -> 4 cols each, ty=tid>>5 -> 4 rows each (4x4 register block).
// LDS: xs 8KB + ws 32KB = 40KB.

__global__ __launch_bounds__(256) void k_gemm(const float* __restrict__ x,
                                              const float* __restrict__ Wt,
                                              const float* __restrict__ dinv,
                                              float* __restrict__ g, int n) {
    __shared__ float xs[32][64];
    __shared__ float ws[64][128];
    const int tid = threadIdx.x;
    const int tx = tid & 31;   // column group: cols 4*tx .. 4*tx+3
    const int ty = tid >> 5;   // row group: rows 4*ty .. 4*ty+3 (ty in 0..7)
    const int row0 = blockIdx.x * 32;

    float acc[4][4] = {{0.f}};

    for (int kb = 0; kb < 128; kb += 64) {
        // stage xs: 32 rows x 64 k = 512 float4, 2 per thread, coalesced
        for (int i = tid; i < 32 * 16; i += 256) {
            int r = i >> 4, c4 = i & 15;
            int row = row0 + r;
            float4 v = make_float4(0.f, 0.f, 0.f, 0.f);
            if (row < n) v = *(const float4*)(x + (long)row * 128 + kb + c4 * 4);
            *(float4*)(&xs[r][c4 * 4]) = v;
        }
        // stage ws: 64 k x 128 j = 2048 float4, 8 per thread, coalesced, conflict-free
        for (int i = tid; i < 64 * 32; i += 256) {
            int r = i >> 5, c4 = i & 31;
            *(float4*)(&ws[r][c4 * 4]) = *(const float4*)(Wt + (long)(kb + r) * 128 + c4 * 4);
        }
        __syncthreads();

        #pragma unroll 4
        for (int k = 0; k < 64; ++k) {
            float4 wv = *(const float4*)(&ws[k][tx * 4]);  // contiguous b128 across lanes
            float xr0 = xs[ty * 4 + 0][k];   // 2-way broadcast per wave: free
            float xr1 = xs[ty * 4 + 1][k];
            float xr2 = xs[ty * 4 + 2][k];
            float xr3 = xs[ty * 4 + 3][k];
            acc[0][0] += xr0 * wv.x; acc[0][1] += xr0 * wv.y; acc[0][2] += xr0 * wv.z; acc[0][3] += xr0 * wv.w;
            acc[1][0] += xr1 * wv.x; acc[1][1] += xr1 * wv.y; acc[1][2] += xr1 * wv.z; acc[1][3] += xr1 * wv.w;
            acc[2][0] += xr2 * wv.x; acc[2][1] += xr2 * wv.y; acc[2][2] += xr2 * wv.z; acc[2][3] += xr2 * wv.w;
            acc[3][0] += xr3 * wv.x; acc[3][1] += xr3 * wv.y; acc[3][2] += xr3 * wv.z; acc[3][3] += xr3 * wv.w;
        }
        __syncthreads();
    }

    #pragma unroll
    for (int r = 0; r < 4; ++r) {
        int row = row0 + ty * 4 + r;
        if (row < n) {
            float s = dinv[row];
            float4 v = make_float4(acc[r][0] * s, acc[r][1] * s, acc[r][2] * s, acc[r][3] * s);
            *(float4*)(g + (long)row * 128 + tx * 4) = v;
        }
    }
}

// ---------------- out init = self-loop message g ----------------

__global__ void k_init_out(const float* __restrict__ g, float* __restrict__ out, long n4) {
    long i = (long)blockIdx.x * TPB + threadIdx.x;
    if (i < n4) ((float4*)out)[i] = ((const float4*)g)[i];
}

// ---------------- edge scatter: out[dst] += g[src] ----------------
// 32 lanes per edge, float4 gather, 4 scalar fire-and-forget atomics.

__global__ void k_scatter(const int* __restrict__ src, const int* __restrict__ dst,
                          const float* __restrict__ g, float* __restrict__ out, int E) {
    long t = (long)blockIdx.x * TPB + threadIdx.x;
    int e = (int)(t >> 5);
    if (e >= E) return;
    int c = ((int)t & 31) << 2;
    int s = src[e], d = dst[e];
    float4 v = *(const float4*)(g + (long)s * 128 + c);
    float* o = out + (long)d * 128 + c;
    atomicAdd(o + 0, v.x);
    atomicAdd(o + 1, v.y);
    atomicAdd(o + 2, v.z);
    atomicAdd(o + 3, v.w);
}

// ---------------- epilogue: out = out * dinv + b ----------------

__global__ void k_final(float* __restrict__ out, const float* __restrict__ dinv,
                        const float* __restrict__ b, int n) {
    long t = (long)blockIdx.x * TPB + threadIdx.x;
    int i = (int)(t >> 5);
    if (i >= n) return;
    int c = ((int)t & 31) << 2;
    float s = dinv[i];
    float4 v = *(const float4*)(out + (long)i * 128 + c);
    float4 bb = *(const float4*)(b + c);
    v.x = v.x * s + bb.x;
    v.y = v.y * s + bb.y;
    v.z = v.z * s + bb.z;
    v.w = v.w * s + bb.w;
    *(float4*)(out + (long)i * 128 + c) = v;
}

extern "C" void kernel_launch(void* const* d_in, const int* in_sizes, int n_in,
                              void* d_out, int out_size, void* d_ws, size_t ws_size,
                              hipStream_t stream) {
    const float* x = (const float*)d_in[0];
    const int*   ei = (const int*)d_in[1];
    // d_in[2] = edge_attr, unused by GCNConv (weight = 1)
    const float* W = (const float*)d_in[3];
    const float* b = (const float*)d_in[4];
    float* out = (float*)d_out;

    const int N = in_sizes[0] / 128;
    const int E = in_sizes[1] / 2;
    const int* src = ei;
    const int* dst = ei + E;

    // workspace layout: deg/dinv [N], Wt [128*128], g [N*128]  (~51.7 MB)
    float* deg = (float*)d_ws;
    float* Wt  = deg + ((N + 255) & ~255);
    float* g   = Wt + 128 * 128;

    k_deg_init<<<(N + TPB - 1) / TPB, TPB, 0, stream>>>(deg, N);
    k_deg_count<<<(E + TPB - 1) / TPB, TPB, 0, stream>>>(dst, deg, E);
    k_dinv<<<(N + TPB - 1) / TPB, TPB, 0, stream>>>(deg, N);
    k_transpose<<<(128 * 128 + TPB - 1) / TPB, TPB, 0, stream>>>(W, Wt);
    k_gemm<<<(N + 31) / 32, TPB, 0, stream>>>(x, Wt, deg, g, N);

    long n4 = (long)N * 32;  // N*128/4 float4s
    k_init_out<<<(int)((n4 + TPB - 1) / TPB), TPB, 0, stream>>>(g, out, n4);

    long st = (long)E * 32;  // 32 threads per edge
    k_scatter<<<(int)((st + TPB - 1) / TPB), TPB, 0, stream>>>(src, dst, g, out, E);

    k_final<<<(int)(((long)N * 32 + TPB - 1) / TPB), TPB, 0, stream>>>(out, deg, b, N);
}

// Round 2
// 461.708 us; speedup vs baseline: 6.3804x; 6.3804x over previous
//
#include <hip/hip_runtime.h>

#define TPB 256

// ================= histogram / normalization =================

__global__ void k_zero_hist(int* __restrict__ hist, int n) {
    int i = blockIdx.x * TPB + threadIdx.x;
    if (i < n) hist[i] = 0;
}

__global__ void k_hist(const int* __restrict__ dst, int* __restrict__ hist, int E) {
    int e = blockIdx.x * TPB + threadIdx.x;
    if (e < E) atomicAdd(&hist[dst[e]], 1);
}

__global__ void k_dinv(const int* __restrict__ hist, float* __restrict__ dinv, int n) {
    int i = blockIdx.x * TPB + threadIdx.x;
    if (i < n) dinv[i] = rsqrtf((float)hist[i] + 1.0f);  // +1 self-loop
}

// ================= exclusive scan of hist (512-elem blocks) =================

__global__ __launch_bounds__(512) void k_scan1(const int* __restrict__ hist,
                                               int* __restrict__ incl,
                                               int* __restrict__ bsum, int n) {
    __shared__ int tmp[2][512];
    int t = threadIdx.x;
    int i = blockIdx.x * 512 + t;
    int v = (i < n) ? hist[i] : 0;
    tmp[0][t] = v;
    __syncthreads();
    int sb = 0;
    for (int d = 1; d < 512; d <<= 1) {
        int val = tmp[sb][t];
        if (t >= d) val += tmp[sb][t - d];
        tmp[sb ^ 1][t] = val;
        sb ^= 1;
        __syncthreads();
    }
    int inc = tmp[sb][t];
    if (i < n) incl[i] = inc;
    if (t == 511) bsum[blockIdx.x] = inc;
}

// single-block exclusive scan of block sums (nb <= 256)
__global__ __launch_bounds__(256) void k_scan2(int* __restrict__ bsum, int nb) {
    __shared__ int tmp[2][256];
    int t = threadIdx.x;
    int v = (t < nb) ? bsum[t] : 0;
    tmp[0][t] = v;
    __syncthreads();
    int sb = 0;
    for (int d = 1; d < 256; d <<= 1) {
        int val = tmp[sb][t];
        if (t >= d) val += tmp[sb][t - d];
        tmp[sb ^ 1][t] = val;
        sb ^= 1;
        __syncthreads();
    }
    if (t < nb) bsum[t] = tmp[sb][t] - v;  // exclusive
}

__global__ void k_scan3(const int* __restrict__ incl, const int* __restrict__ hist,
                        const int* __restrict__ bsum, int* __restrict__ offsets,
                        int* __restrict__ cursor, int n, int E) {
    int i = blockIdx.x * TPB + threadIdx.x;
    if (i < n) {
        int off = incl[i] - hist[i] + bsum[i >> 9];
        offsets[i] = off;
        cursor[i] = off;
    } else if (i == n) {
        offsets[n] = E;
    }
}

// ================= reorder edges by dst (counting sort scatter) =================

__global__ void k_reorder(const int* __restrict__ src, const int* __restrict__ dst,
                          int* __restrict__ cursor, int* __restrict__ sorted_src, int E) {
    int e = blockIdx.x * TPB + threadIdx.x;
    if (e < E) {
        int d = dst[e];
        int pos = atomicAdd(&cursor[d], 1);
        sorted_src[pos] = src[e];
    }
}

// ================= W transpose (one-time, 64 KB) =================

__global__ void k_transpose(const float* __restrict__ W, float* __restrict__ Wt) {
    int idx = blockIdx.x * TPB + threadIdx.x;
    if (idx < 128 * 128) {
        int j = idx >> 7, k = idx & 127;
        Wt[k * 128 + j] = W[idx];
    }
}

// ================= GEMM: g[i][j] = dinv[i] * sum_k x[i][k] * W[j][k] =================

__global__ __launch_bounds__(256) void k_gemm(const float* __restrict__ x,
                                              const float* __restrict__ Wt,
                                              const float* __restrict__ dinv,
                                              float* __restrict__ g, int n) {
    __shared__ float xs[32][64];
    __shared__ float ws[64][128];
    const int tid = threadIdx.x;
    const int tx = tid & 31;
    const int ty = tid >> 5;
    const int row0 = blockIdx.x * 32;

    float acc[4][4] = {{0.f}};

    for (int kb = 0; kb < 128; kb += 64) {
        for (int i = tid; i < 32 * 16; i += 256) {
            int r = i >> 4, c4 = i & 15;
            int row = row0 + r;
            float4 v = make_float4(0.f, 0.f, 0.f, 0.f);
            if (row < n) v = *(const float4*)(x + (long)row * 128 + kb + c4 * 4);
            *(float4*)(&xs[r][c4 * 4]) = v;
        }
        for (int i = tid; i < 64 * 32; i += 256) {
            int r = i >> 5, c4 = i & 31;
            *(float4*)(&ws[r][c4 * 4]) = *(const float4*)(Wt + (long)(kb + r) * 128 + c4 * 4);
        }
        __syncthreads();

        #pragma unroll 4
        for (int k = 0; k < 64; ++k) {
            float4 wv = *(const float4*)(&ws[k][tx * 4]);
            float xr0 = xs[ty * 4 + 0][k];
            float xr1 = xs[ty * 4 + 1][k];
            float xr2 = xs[ty * 4 + 2][k];
            float xr3 = xs[ty * 4 + 3][k];
            acc[0][0] += xr0 * wv.x; acc[0][1] += xr0 * wv.y; acc[0][2] += xr0 * wv.z; acc[0][3] += xr0 * wv.w;
            acc[1][0] += xr1 * wv.x; acc[1][1] += xr1 * wv.y; acc[1][2] += xr1 * wv.z; acc[1][3] += xr1 * wv.w;
            acc[2][0] += xr2 * wv.x; acc[2][1] += xr2 * wv.y; acc[2][2] += xr2 * wv.z; acc[2][3] += xr2 * wv.w;
            acc[3][0] += xr3 * wv.x; acc[3][1] += xr3 * wv.y; acc[3][2] += xr3 * wv.z; acc[3][3] += xr3 * wv.w;
        }
        __syncthreads();
    }

    #pragma unroll
    for (int r = 0; r < 4; ++r) {
        int row = row0 + ty * 4 + r;
        if (row < n) {
            float s = dinv[row];
            float4 v = make_float4(acc[r][0] * s, acc[r][1] * s, acc[r][2] * s, acc[r][3] * s);
            *(float4*)(g + (long)row * 128 + tx * 4) = v;
        }
    }
}

// ================= gather-reduce: out[d] = dinv[d]*(g[d] + sum g[src]) + b =================
// 32 lanes per dst row; float4 per lane; no atomics.

__global__ __launch_bounds__(256) void k_aggregate(const int* __restrict__ sorted_src,
                                                   const int* __restrict__ offsets,
                                                   const float* __restrict__ g,
                                                   const float* __restrict__ dinv,
                                                   const float* __restrict__ b,
                                                   float* __restrict__ out, int n) {
    int group = blockIdx.x * (TPB / 32) + (threadIdx.x >> 5);
    if (group >= n) return;
    int c = (threadIdx.x & 31) << 2;

    int s0 = offsets[group];
    int s1 = offsets[group + 1];

    float4 acc = *(const float4*)(g + (long)group * 128 + c);  // self-loop message

    int e = s0;
    for (; e + 4 <= s1; e += 4) {
        int a0 = sorted_src[e + 0];
        int a1 = sorted_src[e + 1];
        int a2 = sorted_src[e + 2];
        int a3 = sorted_src[e + 3];
        float4 v0 = *(const float4*)(g + (long)a0 * 128 + c);
        float4 v1 = *(const float4*)(g + (long)a1 * 128 + c);
        float4 v2 = *(const float4*)(g + (long)a2 * 128 + c);
        float4 v3 = *(const float4*)(g + (long)a3 * 128 + c);
        acc.x += (v0.x + v1.x) + (v2.x + v3.x);
        acc.y += (v0.y + v1.y) + (v2.y + v3.y);
        acc.z += (v0.z + v1.z) + (v2.z + v3.z);
        acc.w += (v0.w + v1.w) + (v2.w + v3.w);
    }
    for (; e < s1; ++e) {
        int a = sorted_src[e];
        float4 v = *(const float4*)(g + (long)a * 128 + c);
        acc.x += v.x; acc.y += v.y; acc.z += v.z; acc.w += v.w;
    }

    float s = dinv[group];
    float4 bb = *(const float4*)(b + c);
    float4 r;
    r.x = acc.x * s + bb.x;
    r.y = acc.y * s + bb.y;
    r.z = acc.z * s + bb.z;
    r.w = acc.w * s + bb.w;
    *(float4*)(out + (long)group * 128 + c) = r;
}

// ================= launch =================

extern "C" void kernel_launch(void* const* d_in, const int* in_sizes, int n_in,
                              void* d_out, int out_size, void* d_ws, size_t ws_size,
                              hipStream_t stream) {
    const float* x = (const float*)d_in[0];
    const int*   ei = (const int*)d_in[1];
    // d_in[2] = edge_attr (unused; GCN edge weight = 1)
    const float* W = (const float*)d_in[3];
    const float* b = (const float*)d_in[4];
    float* out = (float*)d_out;

    const int N = in_sizes[0] / 128;
    const int E = in_sizes[1] / 2;
    const int* src = ei;
    const int* dst = ei + E;

    const int NB512 = (N + 511) / 512;  // scan blocks (196 for N=100K, <=256 required)

    // ---- workspace carve ----
    char* p = (char*)d_ws;
    auto carve = [&](size_t bytes) { char* q = p; p += (bytes + 255) & ~(size_t)255; return q; };
    int*   hist       = (int*)  carve((size_t)N * 4);
    int*   incl       = (int*)  carve((size_t)N * 4);
    int*   bsum       = (int*)  carve(1024 * 4);
    int*   offsets    = (int*)  carve((size_t)(N + 1) * 4);
    int*   cursor     = (int*)  carve((size_t)N * 4);
    int*   sorted_src = (int*)  carve((size_t)E * 4);
    float* dinv       = (float*)carve((size_t)N * 4);
    float* Wt         = (float*)carve((size_t)128 * 128 * 4);
    float* g          = (float*)carve((size_t)N * 128 * 4);

    int gridN = (N + TPB - 1) / TPB;
    int gridE = (E + TPB - 1) / TPB;

    k_zero_hist<<<gridN, TPB, 0, stream>>>(hist, N);
    k_hist<<<gridE, TPB, 0, stream>>>(dst, hist, E);
    k_dinv<<<gridN, TPB, 0, stream>>>(hist, dinv, N);

    k_scan1<<<NB512, 512, 0, stream>>>(hist, incl, bsum, N);
    k_scan2<<<1, 256, 0, stream>>>(bsum, NB512);
    k_scan3<<<(N + 1 + TPB - 1) / TPB, TPB, 0, stream>>>(incl, hist, bsum, offsets, cursor, N, E);

    k_reorder<<<gridE, TPB, 0, stream>>>(src, dst, cursor, sorted_src, E);

    k_transpose<<<(128 * 128 + TPB - 1) / TPB, TPB, 0, stream>>>(W, Wt);
    k_gemm<<<(N + 31) / 32, TPB, 0, stream>>>(x, Wt, dinv, g, N);

    k_aggregate<<<(N * 32 + TPB - 1) / TPB, TPB, 0, stream>>>(sorted_src, offsets, g, dinv, b, out, N);
}